// Round 14
// baseline (1936.503 us; speedup 1.0000x reference)
//
#include <hip/hip_runtime.h>
#include <hip/hip_fp16.h>

#define NB 3
#define HIDDEN 256
#define INDIM 128
#define NGRAPH 256
#define NCLS 10
#define NMAX 50048
#define EMAX 800000

typedef unsigned short u16;
typedef unsigned long long ull;
typedef _Float16 f16_t;
typedef f16_t f16x8 __attribute__((ext_vector_type(8)));
typedef float f32x4 __attribute__((ext_vector_type(4)));

// ---- static device scratch; intermediates stored f16, computed f32 ----
// Node-interleaved layout: [node][branch][256] (1536 B per node).
// Symbols referenced ONLY inside device code (host passing = r8 crash).
__device__ __align__(16) u16   g_states[(size_t)NMAX * NB * HIDDEN];
__device__ __align__(16) u16   g_agg3 [(size_t)NMAX * NB * HIDDEN];  // layer0: [node][128] compact
__device__ __align__(16) u16   g_xh    [(size_t)NMAX * INDIM];
__device__ __align__(16) u16   g_whin [(size_t)NB * INDIM * HIDDEN];  // Win^T f16 [b][col][k]
__device__ __align__(16) u16   g_whid [(size_t)9 * HIDDEN * HIDDEN];  // Whid^T f16 [(l-1)*3+b][col][k]
__device__ float g_fin   [NGRAPH * HIDDEN];
__device__ float g_dinv  [NMAX];
__device__ float g_ewts  [EMAX];
__device__ int   g_rowptr[NMAX + 1];
__device__ int   g_cidx  [EMAX];
__device__ int   g_cnt   [NMAX];
__device__ int   g_bsum  [64];
__device__ int   g_gs    [NGRAPH];
__device__ int   g_gc    [NGRAPH];

union HU { u16 u; __half h; };
__device__ __forceinline__ float h2f(u16 v) { HU x; x.u = v; return __half2float(x.h); }
__device__ __forceinline__ u16 f2h(float f) { HU x; x.h = __float2half_rn(f); return x.u; }
__device__ __forceinline__ float relu_f(float x) { return x > 0.f ? x : 0.f; }

// acc[0..7] += w * (8 f16 packed in uint4)
__device__ __forceinline__ void fma8(float* acc, uint4 v, float w) {
    unsigned uu[4] = {v.x, v.y, v.z, v.w};
    #pragma unroll
    for (int q = 0; q < 4; ++q) {
        HU lo, hi; lo.u = (u16)(uu[q] & 0xFFFFu); hi.u = (u16)(uu[q] >> 16);
        acc[q * 2 + 0] += w * __half2float(lo.h);
        acc[q * 2 + 1] += w * __half2float(hi.h);
    }
}

// ---------------- init / conversions ----------------
__global__ void zero_cnt_k(int n) {
    int i = blockIdx.x * 256 + threadIdx.x;
    if (i < n) g_cnt[i] = 0;
}
__global__ void zero_gk() {
    int i = threadIdx.x;
    g_gs[i] = 0; g_gc[i] = 0;
}
__global__ void cvt_xh_k(const float* __restrict__ x, int cnt4) {
    int i = blockIdx.x * 256 + threadIdx.x;
    if (i >= cnt4) return;
    float4 v = ((const float4*)x)[i];
    ushort4 o; o.x = f2h(v.x); o.y = f2h(v.y); o.z = f2h(v.z); o.w = f2h(v.w);
    ((ushort4*)g_xh)[i] = o;
}
// LDS-tiled transpose: src [B][K][256] f32 -> dst [B][256][K] f16.
__global__ void cvt_wt_k(const float* __restrict__ src, int which, int K) {
    __shared__ u16 tile[32][33];
    int k0 = blockIdx.x * 32, c0 = blockIdx.y * 32, b = blockIdx.z;
    int t = threadIdx.x;
    int tc = t & 31, tk = t >> 5;
    const float* S = src + (size_t)b * K * 256;
    #pragma unroll
    for (int q = 0; q < 4; ++q) {
        int kk = tk * 4 + q;
        tile[kk][tc] = f2h(S[(size_t)(k0 + kk) * 256 + c0 + tc]);
    }
    __syncthreads();
    u16* D = (which ? g_whid : g_whin) + (size_t)b * K * 256;
    int kx = t & 31, cg = t >> 5;
    #pragma unroll
    for (int q = 0; q < 4; ++q) {
        int c = c0 + cg * 4 + q;
        D[(size_t)c * K + k0 + kx] = tile[kx][cg * 4 + q];
    }
}

// ---------------- CSR build ----------------
__global__ void count_edges_k(const int* __restrict__ col, int E) {
    int i = blockIdx.x * 256 + threadIdx.x;
    if (i < E) atomicAdd(&g_cnt[col[i]], 1);
}
__global__ void dinv_k(int n) {
    int i = blockIdx.x * 256 + threadIdx.x;
    if (i < n) g_dinv[i] = rsqrtf((float)(g_cnt[i] + 1));
}
__global__ __launch_bounds__(1024) void scan1_k(int n) {
    __shared__ int sm[1024];
    int blk = blockIdx.x, t = threadIdx.x;
    int i = blk * 1024 + t;
    int v = (i < n) ? g_cnt[i] : 0;
    sm[t] = v;
    __syncthreads();
    for (int off = 1; off < 1024; off <<= 1) {
        int u = (t >= off) ? sm[t - off] : 0;
        __syncthreads();
        sm[t] += u;
        __syncthreads();
    }
    if (i < n) g_rowptr[i + 1] = sm[t];
    if (t == 1023) g_bsum[blk] = sm[t];
    if (blk == 0 && t == 0) g_rowptr[0] = 0;
}
__global__ void scan2_k(int nblk) {
    int t = threadIdx.x;
    int v = (t < nblk) ? g_bsum[t] : 0;
    #pragma unroll
    for (int off = 1; off < 64; off <<= 1) {
        int u = __shfl_up(v, off);
        if (t >= off) v += u;
    }
    if (t < nblk) g_bsum[t] = v;
}
__global__ void scan3_k(int n) {
    int i = blockIdx.x * 256 + threadIdx.x;
    if (i >= n) return;
    int blk = i >> 10;
    if (blk > 0) g_rowptr[i + 1] += g_bsum[blk - 1];
}
__global__ void fill_csr_k(const int* __restrict__ row, const int* __restrict__ col, int E) {
    int i = blockIdx.x * 256 + threadIdx.x;
    if (i >= E) return;
    int r = row[i], c = col[i];
    int pos = g_rowptr[c] + atomicAdd(&g_cnt[c], 1);
    g_cidx[pos] = r;
    g_ewts[pos] = g_dinv[r] * g_dinv[c];
}

// ---------------- aggregation: interleaved layout, 2 edges in flight ----------------
__global__ __launch_bounds__(256) void agg256x3_k(int n) {
    int node = blockIdx.x * 4 + (threadIdx.x >> 6);
    if (node >= n) return;
    int lane = threadIdx.x & 63;
    int half = lane >> 5;
    int li   = lane & 31;
    const uint4* Sv = (const uint4*)g_states;
    float acc0[8] = {0,0,0,0,0,0,0,0}, acc1[8] = {0,0,0,0,0,0,0,0}, acc2[8] = {0,0,0,0,0,0,0,0};
    int e0 = g_rowptr[node], deg = g_rowptr[node + 1] - e0;
    int m = deg + 1;
    int j = half;
    if (half == 0) {
        float di = g_dinv[node];
        float w0 = di * di;
        size_t base = (size_t)node * 96 + li;
        fma8(acc0, Sv[base], w0);
        fma8(acc1, Sv[base + 32], w0);
        fma8(acc2, Sv[base + 64], w0);
        j = 2;
    }
    #pragma unroll 2
    for (; j < m; j += 2) {
        int s = g_cidx[e0 + j - 1];
        float w = g_ewts[e0 + j - 1];
        size_t base = (size_t)s * 96 + li;
        uint4 v0 = Sv[base], v1 = Sv[base + 32], v2 = Sv[base + 64];
        fma8(acc0, v0, w); fma8(acc1, v1, w); fma8(acc2, v2, w);
    }
    #pragma unroll
    for (int q = 0; q < 8; ++q) {
        acc0[q] += __shfl_xor(acc0[q], 32);
        acc1[q] += __shfl_xor(acc1[q], 32);
        acc2[q] += __shfl_xor(acc2[q], 32);
    }
    if (half == 0) {
        uint4* Av = (uint4*)g_agg3;
        size_t base = (size_t)node * 96 + li;
        uint4 o;
        unsigned* ou = (unsigned*)&o;
        #pragma unroll
        for (int q = 0; q < 4; ++q) ou[q] = (unsigned)f2h(acc0[q*2]) | ((unsigned)f2h(acc0[q*2+1]) << 16);
        Av[base] = o;
        #pragma unroll
        for (int q = 0; q < 4; ++q) ou[q] = (unsigned)f2h(acc1[q*2]) | ((unsigned)f2h(acc1[q*2+1]) << 16);
        Av[base + 32] = o;
        #pragma unroll
        for (int q = 0; q < 4; ++q) ou[q] = (unsigned)f2h(acc2[q*2]) | ((unsigned)f2h(acc2[q*2+1]) << 16);
        Av[base + 64] = o;
    }
}

__global__ __launch_bounds__(256) void agg128_k(int n) {
    int node = blockIdx.x * 4 + (threadIdx.x >> 6);
    if (node >= n) return;
    int lane = threadIdx.x & 63;
    int grp = lane >> 4;
    int li  = lane & 15;
    const uint4* Xv = (const uint4*)g_xh;
    float acc[8] = {0,0,0,0,0,0,0,0};
    int e0 = g_rowptr[node], deg = g_rowptr[node + 1] - e0;
    int m = deg + 1;
    int j = grp;
    if (grp == 0) {
        float di = g_dinv[node];
        fma8(acc, Xv[(size_t)node * 16 + li], di * di);
        j = 4;
    }
    #pragma unroll 2
    for (; j < m; j += 4) {
        int s = g_cidx[e0 + j - 1];
        float w = g_ewts[e0 + j - 1];
        fma8(acc, Xv[(size_t)s * 16 + li], w);
    }
    #pragma unroll
    for (int q = 0; q < 8; ++q) {
        acc[q] += __shfl_xor(acc[q], 16);
        acc[q] += __shfl_xor(acc[q], 32);
    }
    if (grp == 0) {
        uint4 o; unsigned* ou = (unsigned*)&o;
        #pragma unroll
        for (int q = 0; q < 4; ++q) ou[q] = (unsigned)f2h(acc[q*2]) | ((unsigned)f2h(acc[q*2+1]) << 16);
        ((uint4*)g_agg3)[(size_t)node * 16 + li] = o;
    }
}

// ---------------- interleaved exact top-128 masks, early-exit search ----------------
template<int CNT>
__device__ __forceinline__ void topk_multi(const ushort4* hu, const float4* v, float4* out) {
    int lane = threadIdx.x & 63;
    unsigned lo[CNT], hi[CNT]; int cge[CNT];
    #pragma unroll
    for (int s = 0; s < CNT; ++s) {
        unsigned mx = max(max((unsigned)hu[s].x, (unsigned)hu[s].y),
                          max((unsigned)hu[s].z, (unsigned)hu[s].w));
        #pragma unroll
        for (int off = 32; off >= 1; off >>= 1)
            mx = max(mx, (unsigned)__shfl_xor((int)mx, off));
        lo[s] = 0; hi[s] = mx; cge[s] = 256;
    }
    for (int it = 0; it < 15; ++it) {
        #pragma unroll
        for (int s = 0; s < CNT; ++s) {
            if (cge[s] == 128 || lo[s] >= hi[s]) continue;   // wave-uniform skip
            unsigned mid = (lo[s] + hi[s] + 1) >> 1;
            int c = __popcll(__ballot(hu[s].x >= mid)) + __popcll(__ballot(hu[s].y >= mid))
                  + __popcll(__ballot(hu[s].z >= mid)) + __popcll(__ballot(hu[s].w >= mid));
            if (c >= 128) { lo[s] = mid; cge[s] = c; } else hi[s] = mid - 1;
        }
    }
    #pragma unroll
    for (int s = 0; s < CNT; ++s) {
        unsigned thr = lo[s];
        unsigned a0 = hu[s].x, a1 = hu[s].y, a2 = hu[s].z, a3 = hu[s].w;
        float4 r;
        if (cge[s] == 128) {
            r.x = (a0 >= thr) ? v[s].x : 0.f;
            r.y = (a1 >= thr) ? v[s].y : 0.f;
            r.z = (a2 >= thr) ? v[s].z : 0.f;
            r.w = (a3 >= thr) ? v[s].w : 0.f;
        } else {            // trim ties: keep lowest element indices among == thr
            ull b0 = __ballot(a0 == thr), b1 = __ballot(a1 == thr);
            ull b2 = __ballot(a2 == thr), b3 = __ballot(a3 == thr);
            int cgt = __popcll(__ballot(a0 > thr)) + __popcll(__ballot(a1 > thr))
                    + __popcll(__ballot(a2 > thr)) + __popcll(__ballot(a3 > thr));
            int need = 128 - cgt;
            ull below = (lane == 0) ? 0ull : (~0ull >> (64 - lane));
            int base = __popcll(b0 & below) + __popcll(b1 & below)
                     + __popcll(b2 & below) + __popcll(b3 & below);
            int o0 = (int)((b0 >> lane) & 1), o1 = (int)((b1 >> lane) & 1), o2 = (int)((b2 >> lane) & 1);
            int p0 = base, p1 = base + o0, p2 = p1 + o1, p3 = p2 + o2;
            r.x = (a0 > thr || (a0 == thr && p0 < need)) ? v[s].x : 0.f;
            r.y = (a1 > thr || (a1 == thr && p1 < need)) ? v[s].y : 0.f;
            r.z = (a2 > thr || (a2 == thr && p2 < need)) ? v[s].z : 0.f;
            r.w = (a3 > thr || (a3 == thr && p3 < need)) ? v[s].w : 0.f;
        }
        out[s] = r;
    }
}

__device__ __forceinline__ float4 dec4(ushort4 h) {
    float4 r; r.x = h2f(h.x); r.y = h2f(h.y); r.z = h2f(h.z); r.w = h2f(h.w);
    return r;
}
__device__ __forceinline__ void st4h(u16* p, size_t off, float4 v) {
    ushort4 o; o.x = f2h(v.x); o.y = f2h(v.y); o.z = f2h(v.z); o.w = f2h(v.w);
    ((ushort4*)p)[off] = o;
}

// ---------------- fused GEMM + fuse: one kernel per layer ----------------
// Block = 32 nodes. Phase 1: 3-branch GEMM into LDS (f16, identical rounding to
// the old props global store). Phase 2: per-node top-k fuse; states updated.
// LDS row stride 776 u16 breaks the 4-way bank alias of the natural 768 stride.
#define LDSW 776
template<int K, bool L0>
__global__ __launch_bounds__(256) void gemm_fuse_k(int wsel, int rowStride, int brMul,
        const float* __restrict__ bias0, const float* __restrict__ gate_logit, int n) {
    __shared__ u16 lds_p[32 * LDSW];
    int t = threadIdx.x, l = t & 63, w = t >> 6;
    int row0 = blockIdx.x * 32;
    int mrow = l & 15;
    int kg = (l >> 4) * 8;
    int rb = (l >> 4) * 4;

    for (int br = 0; br < NB; ++br) {
        const f16_t* A  = (const f16_t*)g_agg3 + (size_t)br * brMul;
        const f16_t* Wt = (wsel < 0) ? (const f16_t*)g_whin + (size_t)br * K * 256
                                     : (const f16_t*)g_whid + (size_t)(wsel + br) * K * 256;
        const float* bias = bias0 + (size_t)br * 256;
        f32x4 acc[2][4];
        #pragma unroll
        for (int rt = 0; rt < 2; ++rt)
            #pragma unroll
            for (int ct = 0; ct < 4; ++ct) acc[rt][ct] = (f32x4){0.f, 0.f, 0.f, 0.f};
        for (int k0 = 0; k0 < K; k0 += 32) {
            f16x8 af[2], bf[4];
            #pragma unroll
            for (int rt = 0; rt < 2; ++rt) {
                int r = row0 + rt * 16 + mrow;   // < NMAX always (NMAX = 1564*32)
                af[rt] = *(const f16x8*)(A + (size_t)r * rowStride + k0 + kg);
            }
            #pragma unroll
            for (int ct = 0; ct < 4; ++ct) {
                int c = w * 64 + ct * 16 + mrow;
                bf[ct] = *(const f16x8*)(Wt + (size_t)c * K + k0 + kg);
            }
            #pragma unroll
            for (int rt = 0; rt < 2; ++rt)
                #pragma unroll
                for (int ct = 0; ct < 4; ++ct)
                    acc[rt][ct] = __builtin_amdgcn_mfma_f32_16x16x32_f16(af[rt], bf[ct], acc[rt][ct], 0, 0, 0);
        }
        #pragma unroll
        for (int ct = 0; ct < 4; ++ct) {
            int c = w * 64 + ct * 16 + mrow;
            float bv = bias[c];
            #pragma unroll
            for (int rt = 0; rt < 2; ++rt) {
                #pragma unroll
                for (int q = 0; q < 4; ++q) {
                    int ndl = rt * 16 + rb + q;     // local node 0..31
                    lds_p[ndl * LDSW + br * 256 + c] = f2h(relu_f(acc[rt][ct][q] + bv));
                }
            }
        }
    }
    __syncthreads();

    // fuse phase: 8 nodes per wave; lane l owns ushort4 cols 4l..4l+3
    float g = 1.f / (1.f + expf(-gate_logit[0]));
    for (int i = 0; i < 8; ++i) {
        int ndl = w * 8 + i;
        int node = row0 + ndl;
        if (node >= n) break;                        // wave-uniform
        const u16* LP = lds_p + ndl * LDSW;
        size_t base4 = (size_t)node * 192 + l;
        ushort4 hu[L0 ? 3 : 6]; float4 v[L0 ? 3 : 6], m[L0 ? 3 : 6];
        hu[0] = ((const ushort4*)LP)[l];
        hu[1] = ((const ushort4*)(LP + 256))[l];
        hu[2] = ((const ushort4*)(LP + 512))[l];
        if constexpr (!L0) {
            const ushort4* S = (const ushort4*)g_states;
            hu[3] = S[base4]; hu[4] = S[base4 + 64]; hu[5] = S[base4 + 128];
        }
        #pragma unroll
        for (int s = 0; s < (L0 ? 3 : 6); ++s) v[s] = dec4(hu[s]);
        topk_multi<L0 ? 3 : 6>(hu, v, m);
        float4 o0, o1, o2;
        if constexpr (L0) {
            o0.x = relu_f(v[0].x + g * m[1].x); o0.y = relu_f(v[0].y + g * m[1].y);
            o0.z = relu_f(v[0].z + g * m[1].z); o0.w = relu_f(v[0].w + g * m[1].w);
            o1.x = relu_f(v[1].x + g * (m[0].x + m[2].x)); o1.y = relu_f(v[1].y + g * (m[0].y + m[2].y));
            o1.z = relu_f(v[1].z + g * (m[0].z + m[2].z)); o1.w = relu_f(v[1].w + g * (m[0].w + m[2].w));
            o2.x = relu_f(v[2].x + g * m[1].x); o2.y = relu_f(v[2].y + g * m[1].y);
            o2.z = relu_f(v[2].z + g * m[1].z); o2.w = relu_f(v[2].w + g * m[1].w);
        } else {
            o0.x = relu_f(v[0].x + g * (m[3].x + m[1].x + m[4].x));
            o0.y = relu_f(v[0].y + g * (m[3].y + m[1].y + m[4].y));
            o0.z = relu_f(v[0].z + g * (m[3].z + m[1].z + m[4].z));
            o0.w = relu_f(v[0].w + g * (m[3].w + m[1].w + m[4].w));
            o1.x = relu_f(v[1].x + g * (m[4].x + m[0].x + m[3].x + m[2].x + m[5].x));
            o1.y = relu_f(v[1].y + g * (m[4].y + m[0].y + m[3].y + m[2].y + m[5].y));
            o1.z = relu_f(v[1].z + g * (m[4].z + m[0].z + m[3].z + m[2].z + m[5].z));
            o1.w = relu_f(v[1].w + g * (m[4].w + m[0].w + m[3].w + m[2].w + m[5].w));
            o2.x = relu_f(v[2].x + g * (m[5].x + m[1].x + m[4].x));
            o2.y = relu_f(v[2].y + g * (m[5].y + m[1].y + m[4].y));
            o2.z = relu_f(v[2].z + g * (m[5].z + m[1].z + m[4].z));
            o2.w = relu_f(v[2].w + g * (m[5].w + m[1].w + m[4].w));
        }
        st4h(g_states, base4, o0); st4h(g_states, base4 + 64, o1); st4h(g_states, base4 + 128, o2);
    }
}

// ---------------- readout ----------------
__global__ void gbounds_k(const int* __restrict__ batch, int n) {
    int i = blockIdx.x * 256 + threadIdx.x;
    if (i >= n) return;
    int g = batch[i];
    atomicAdd(&g_gc[g], 1);
    if (i == 0 || batch[i - 1] != g) g_gs[g] = i;
}

__global__ __launch_bounds__(256) void greduce_k(float* __restrict__ outfin, int n) {
    __shared__ float sums[768];
    int g = blockIdx.x, t = threadIdx.x;
    int st = g_gs[g], c = g_gc[g];
    if (t < 192) {
        const ushort4* S = (const ushort4*)g_states;
        float a0 = 0.f, a1 = 0.f, a2 = 0.f, a3 = 0.f;
        for (int i = st; i < st + c; ++i) {
            ushort4 v = S[(size_t)i * 192 + t];
            a0 += h2f(v.x); a1 += h2f(v.y); a2 += h2f(v.z); a3 += h2f(v.w);
        }
        sums[t * 4 + 0] = a0; sums[t * 4 + 1] = a1;
        sums[t * 4 + 2] = a2; sums[t * 4 + 3] = a3;
    }
    __syncthreads();
    float r = (sums[t] + sums[256 + t] + sums[512 + t]) / (3.0f * (float)(c > 0 ? c : 1));
    g_fin[g * 256 + t] = r;
    outfin[(size_t)g * 256 + t] = r;
}

__global__ void logits_k(const float* __restrict__ Wc, const float* __restrict__ bc,
                         float* __restrict__ out) {
    int idx = blockIdx.x * 256 + threadIdx.x;
    if (idx >= NGRAPH * NCLS) return;
    int g = idx / NCLS, c = idx % NCLS;
    float s = bc[c];
    for (int k = 0; k < 256; ++k) s += g_fin[g * 256 + k] * Wc[k * NCLS + c];
    out[idx] = s;
}

// ---------------- launch ----------------
extern "C" void kernel_launch(void* const* d_in, const int* in_sizes, int n_in,
                              void* d_out, int out_size, void* d_ws, size_t ws_size,
                              hipStream_t stream) {
    const float* x       = (const float*)d_in[0];
    const int*   eidx    = (const int*)d_in[1];
    const int*   batch   = (const int*)d_in[2];
    const float* Win     = (const float*)d_in[3];
    const float* b_in    = (const float*)d_in[4];
    const float* Whid    = (const float*)d_in[5];
    const float* bhid    = (const float*)d_in[6];
    const float* gate_l  = (const float*)d_in[7];
    const float* Wc      = (const float*)d_in[8];
    const float* bc      = (const float*)d_in[9];
    float* out = (float*)d_out;

    const int n = in_sizes[0] / INDIM;       // 50000
    const int E = in_sizes[1] / 2;           // 800000
    if (n > NMAX || E > EMAX) return;
    const int* erow = eidx;
    const int* ecol = eidx + E;

    float* outfin = out + NGRAPH * NCLS;

    const int TB = 256;
    dim3 b256(TB);
    int nblkN = (n + TB - 1) / TB;
    int eblk  = (E + TB - 1) / TB;
    int nblk4 = (n + 3) / 4;
    int sblk  = (n + 1023) / 1024;
    int gfblk = (n + 31) / 32;
    dim3 wgin(INDIM / 32, HIDDEN / 32, NB);
    dim3 wghid(HIDDEN / 32, HIDDEN / 32, 9);

    // --- conversions + CSR build ---
    zero_cnt_k<<<nblkN, b256, 0, stream>>>(n);
    cvt_xh_k<<<(n * INDIM / 4 + TB - 1) / TB, b256, 0, stream>>>(x, n * INDIM / 4);
    cvt_wt_k<<<wgin, b256, 0, stream>>>(Win, 0, INDIM);
    cvt_wt_k<<<wghid, b256, 0, stream>>>(Whid, 1, HIDDEN);
    count_edges_k<<<eblk, b256, 0, stream>>>(ecol, E);
    dinv_k<<<nblkN, b256, 0, stream>>>(n);
    scan1_k<<<sblk, 1024, 0, stream>>>(n);
    scan2_k<<<1, 64, 0, stream>>>(sblk);
    scan3_k<<<nblkN, b256, 0, stream>>>(n);
    zero_cnt_k<<<nblkN, b256, 0, stream>>>(n);
    fill_csr_k<<<eblk, b256, 0, stream>>>(erow, ecol, E);

    // --- layer 0: agg(x) compact [n][128]; fused GEMM+fuse ---
    agg128_k<<<nblk4, b256, 0, stream>>>(n);
    gemm_fuse_k<INDIM, true><<<gfblk, b256, 0, stream>>>(-1, INDIM, 0, b_in, gate_l, n);

    // --- layers 1..3 ---
    for (int l = 1; l < 4; ++l) {
        agg256x3_k<<<nblk4, b256, 0, stream>>>(n);
        gemm_fuse_k<HIDDEN, false><<<gfblk, b256, 0, stream>>>((l - 1) * NB, NB * HIDDEN, HIDDEN,
                bhid + (size_t)(l - 1) * NB * HIDDEN, gate_l, n);
    }

    // --- readout ---
    zero_gk<<<1, 256, 0, stream>>>();
    gbounds_k<<<nblkN, b256, 0, stream>>>(batch, n);
    greduce_k<<<NGRAPH, b256, 0, stream>>>(outfin, n);
    logits_k<<<(NGRAPH * NCLS + TB - 1) / TB, b256, 0, stream>>>(Wc, bc, out);
}

// Round 15
// 1701.059 us; speedup vs baseline: 1.1384x; 1.1384x over previous
//
#include <hip/hip_runtime.h>
#include <hip/hip_fp16.h>

#define NB 3
#define HIDDEN 256
#define INDIM 128
#define NGRAPH 256
#define NCLS 10
#define NMAX 50048
#define EMAX 800000

typedef unsigned short u16;
typedef unsigned long long ull;
typedef _Float16 f16_t;
typedef f16_t f16x8 __attribute__((ext_vector_type(8)));
typedef float f32x4 __attribute__((ext_vector_type(4)));

// ---- static device scratch; intermediates stored f16, computed f32 ----
// Node-interleaved layout: [node][branch][256] (1536 B per node).
// Symbols referenced ONLY inside device code (host passing = r8 crash).
__device__ __align__(16) u16   g_states[(size_t)NMAX * NB * HIDDEN];
__device__ __align__(16) u16   g_props [(size_t)NMAX * NB * HIDDEN];
__device__ __align__(16) u16   g_agg3 [(size_t)NMAX * NB * HIDDEN];  // layer0: [node][128] compact
__device__ __align__(16) u16   g_xh    [(size_t)NMAX * INDIM];
__device__ __align__(16) u16   g_whin [(size_t)NB * INDIM * HIDDEN];  // Win^T f16 [b][col][k]
__device__ __align__(16) u16   g_whid [(size_t)9 * HIDDEN * HIDDEN];  // Whid^T f16 [(l-1)*3+b][col][k]
__device__ float g_fin   [NGRAPH * HIDDEN];
__device__ float g_dinv  [NMAX];
__device__ float g_ewts  [EMAX];
__device__ int   g_rowptr[NMAX + 1];
__device__ int   g_cidx  [EMAX];
__device__ int   g_cnt   [NMAX];
__device__ int   g_bsum  [64];
__device__ int   g_gs    [NGRAPH];
__device__ int   g_gc    [NGRAPH];

union HU { u16 u; __half h; };
__device__ __forceinline__ float h2f(u16 v) { HU x; x.u = v; return __half2float(x.h); }
__device__ __forceinline__ u16 f2h(float f) { HU x; x.h = __float2half_rn(f); return x.u; }
__device__ __forceinline__ float relu_f(float x) { return x > 0.f ? x : 0.f; }

// acc[0..7] += w * (8 f16 packed in uint4)
__device__ __forceinline__ void fma8(float* acc, uint4 v, float w) {
    unsigned uu[4] = {v.x, v.y, v.z, v.w};
    #pragma unroll
    for (int q = 0; q < 4; ++q) {
        HU lo, hi; lo.u = (u16)(uu[q] & 0xFFFFu); hi.u = (u16)(uu[q] >> 16);
        acc[q * 2 + 0] += w * __half2float(lo.h);
        acc[q * 2 + 1] += w * __half2float(hi.h);
    }
}

// ---------------- init / conversions ----------------
__global__ void zero_cnt_k(int n) {
    int i = blockIdx.x * 256 + threadIdx.x;
    if (i < n) g_cnt[i] = 0;
}
__global__ void zero_gk() {
    int i = threadIdx.x;
    g_gs[i] = 0; g_gc[i] = 0;
}
__global__ void cvt_xh_k(const float* __restrict__ x, int cnt4) {
    int i = blockIdx.x * 256 + threadIdx.x;
    if (i >= cnt4) return;
    float4 v = ((const float4*)x)[i];
    ushort4 o; o.x = f2h(v.x); o.y = f2h(v.y); o.z = f2h(v.z); o.w = f2h(v.w);
    ((ushort4*)g_xh)[i] = o;
}
// LDS-tiled transpose: src [B][K][256] f32 -> dst [B][256][K] f16.
__global__ void cvt_wt_k(const float* __restrict__ src, int which, int K) {
    __shared__ u16 tile[32][33];
    int k0 = blockIdx.x * 32, c0 = blockIdx.y * 32, b = blockIdx.z;
    int t = threadIdx.x;
    int tc = t & 31, tk = t >> 5;
    const float* S = src + (size_t)b * K * 256;
    #pragma unroll
    for (int q = 0; q < 4; ++q) {
        int kk = tk * 4 + q;
        tile[kk][tc] = f2h(S[(size_t)(k0 + kk) * 256 + c0 + tc]);
    }
    __syncthreads();
    u16* D = (which ? g_whid : g_whin) + (size_t)b * K * 256;
    int kx = t & 31, cg = t >> 5;
    #pragma unroll
    for (int q = 0; q < 4; ++q) {
        int c = c0 + cg * 4 + q;
        D[(size_t)c * K + k0 + kx] = tile[kx][cg * 4 + q];
    }
}

// ---------------- CSR build ----------------
__global__ void count_edges_k(const int* __restrict__ col, int E) {
    int i = blockIdx.x * 256 + threadIdx.x;
    if (i < E) atomicAdd(&g_cnt[col[i]], 1);
}
__global__ void dinv_k(int n) {
    int i = blockIdx.x * 256 + threadIdx.x;
    if (i < n) g_dinv[i] = rsqrtf((float)(g_cnt[i] + 1));
}
__global__ __launch_bounds__(1024) void scan1_k(int n) {
    __shared__ int sm[1024];
    int blk = blockIdx.x, t = threadIdx.x;
    int i = blk * 1024 + t;
    int v = (i < n) ? g_cnt[i] : 0;
    sm[t] = v;
    __syncthreads();
    for (int off = 1; off < 1024; off <<= 1) {
        int u = (t >= off) ? sm[t - off] : 0;
        __syncthreads();
        sm[t] += u;
        __syncthreads();
    }
    if (i < n) g_rowptr[i + 1] = sm[t];
    if (t == 1023) g_bsum[blk] = sm[t];
    if (blk == 0 && t == 0) g_rowptr[0] = 0;
}
__global__ void scan2_k(int nblk) {
    int t = threadIdx.x;
    int v = (t < nblk) ? g_bsum[t] : 0;
    #pragma unroll
    for (int off = 1; off < 64; off <<= 1) {
        int u = __shfl_up(v, off);
        if (t >= off) v += u;
    }
    if (t < nblk) g_bsum[t] = v;
}
__global__ void scan3_k(int n) {
    int i = blockIdx.x * 256 + threadIdx.x;
    if (i >= n) return;
    int blk = i >> 10;
    if (blk > 0) g_rowptr[i + 1] += g_bsum[blk - 1];
}
__global__ void fill_csr_k(const int* __restrict__ row, const int* __restrict__ col, int E) {
    int i = blockIdx.x * 256 + threadIdx.x;
    if (i >= E) return;
    int r = row[i], c = col[i];
    int pos = g_rowptr[c] + atomicAdd(&g_cnt[c], 1);
    g_cidx[pos] = r;
    g_ewts[pos] = g_dinv[r] * g_dinv[c];
}

// ---------------- aggregation: interleaved layout, 2 edges in flight ----------------
__global__ __launch_bounds__(256) void agg256x3_k(int n) {
    int node = blockIdx.x * 4 + (threadIdx.x >> 6);
    if (node >= n) return;
    int lane = threadIdx.x & 63;
    int half = lane >> 5;
    int li   = lane & 31;
    const uint4* Sv = (const uint4*)g_states;
    float acc0[8] = {0,0,0,0,0,0,0,0}, acc1[8] = {0,0,0,0,0,0,0,0}, acc2[8] = {0,0,0,0,0,0,0,0};
    int e0 = g_rowptr[node], deg = g_rowptr[node + 1] - e0;
    int m = deg + 1;
    int j = half;
    if (half == 0) {
        float di = g_dinv[node];
        float w0 = di * di;
        size_t base = (size_t)node * 96 + li;
        fma8(acc0, Sv[base], w0);
        fma8(acc1, Sv[base + 32], w0);
        fma8(acc2, Sv[base + 64], w0);
        j = 2;
    }
    #pragma unroll 2
    for (; j < m; j += 2) {
        int s = g_cidx[e0 + j - 1];
        float w = g_ewts[e0 + j - 1];
        size_t base = (size_t)s * 96 + li;
        uint4 v0 = Sv[base], v1 = Sv[base + 32], v2 = Sv[base + 64];
        fma8(acc0, v0, w); fma8(acc1, v1, w); fma8(acc2, v2, w);
    }
    #pragma unroll
    for (int q = 0; q < 8; ++q) {
        acc0[q] += __shfl_xor(acc0[q], 32);
        acc1[q] += __shfl_xor(acc1[q], 32);
        acc2[q] += __shfl_xor(acc2[q], 32);
    }
    if (half == 0) {
        uint4* Av = (uint4*)g_agg3;
        size_t base = (size_t)node * 96 + li;
        uint4 o;
        unsigned* ou = (unsigned*)&o;
        #pragma unroll
        for (int q = 0; q < 4; ++q) ou[q] = (unsigned)f2h(acc0[q*2]) | ((unsigned)f2h(acc0[q*2+1]) << 16);
        Av[base] = o;
        #pragma unroll
        for (int q = 0; q < 4; ++q) ou[q] = (unsigned)f2h(acc1[q*2]) | ((unsigned)f2h(acc1[q*2+1]) << 16);
        Av[base + 32] = o;
        #pragma unroll
        for (int q = 0; q < 4; ++q) ou[q] = (unsigned)f2h(acc2[q*2]) | ((unsigned)f2h(acc2[q*2+1]) << 16);
        Av[base + 64] = o;
    }
}

__global__ __launch_bounds__(256) void agg128_k(int n) {
    int node = blockIdx.x * 4 + (threadIdx.x >> 6);
    if (node >= n) return;
    int lane = threadIdx.x & 63;
    int grp = lane >> 4;
    int li  = lane & 15;
    const uint4* Xv = (const uint4*)g_xh;
    float acc[8] = {0,0,0,0,0,0,0,0};
    int e0 = g_rowptr[node], deg = g_rowptr[node + 1] - e0;
    int m = deg + 1;
    int j = grp;
    if (grp == 0) {
        float di = g_dinv[node];
        fma8(acc, Xv[(size_t)node * 16 + li], di * di);
        j = 4;
    }
    #pragma unroll 2
    for (; j < m; j += 4) {
        int s = g_cidx[e0 + j - 1];
        float w = g_ewts[e0 + j - 1];
        fma8(acc, Xv[(size_t)s * 16 + li], w);
    }
    #pragma unroll
    for (int q = 0; q < 8; ++q) {
        acc[q] += __shfl_xor(acc[q], 16);
        acc[q] += __shfl_xor(acc[q], 32);
    }
    if (grp == 0) {
        uint4 o; unsigned* ou = (unsigned*)&o;
        #pragma unroll
        for (int q = 0; q < 4; ++q) ou[q] = (unsigned)f2h(acc[q*2]) | ((unsigned)f2h(acc[q*2+1]) << 16);
        ((uint4*)g_agg3)[(size_t)node * 16 + li] = o;
    }
}

// ---------------- MFMA GEMM ----------------
template<int K>
__global__ __launch_bounds__(256) void gemm_mfma_k(int wsel, int rowStride, int brMul,
        const float* __restrict__ bias0, int n) {
    int br = blockIdx.y;
    const f16_t* A  = (const f16_t*)g_agg3 + (size_t)br * brMul;
    const f16_t* Wt = (wsel < 0) ? (const f16_t*)g_whin + (size_t)br * K * 256
                                 : (const f16_t*)g_whid + (size_t)(wsel + br) * K * 256;
    const float* bias = bias0 + (size_t)br * 256;
    u16* C = g_props + (size_t)br * 256;
    int t = threadIdx.x, l = t & 63, w = t >> 6;
    int row0 = blockIdx.x * 64;
    int c0 = w * 64;
    int mrow = l & 15;
    int kg = (l >> 4) * 8;
    f32x4 acc[4][4];
    #pragma unroll
    for (int rt = 0; rt < 4; ++rt)
        #pragma unroll
        for (int ct = 0; ct < 4; ++ct) acc[rt][ct] = (f32x4){0.f, 0.f, 0.f, 0.f};

    for (int k0 = 0; k0 < K; k0 += 32) {
        f16x8 af[4], bf[4];
        #pragma unroll
        for (int rt = 0; rt < 4; ++rt) {
            int r = row0 + rt * 16 + mrow;
            af[rt] = *(const f16x8*)(A + (size_t)r * rowStride + k0 + kg);
        }
        #pragma unroll
        for (int ct = 0; ct < 4; ++ct) {
            int c = c0 + ct * 16 + mrow;
            bf[ct] = *(const f16x8*)(Wt + (size_t)c * K + k0 + kg);
        }
        #pragma unroll
        for (int rt = 0; rt < 4; ++rt)
            #pragma unroll
            for (int ct = 0; ct < 4; ++ct)
                acc[rt][ct] = __builtin_amdgcn_mfma_f32_16x16x32_f16(af[rt], bf[ct], acc[rt][ct], 0, 0, 0);
    }
    int rb = (l >> 4) * 4;
    #pragma unroll
    for (int ct = 0; ct < 4; ++ct) {
        int c = c0 + ct * 16 + mrow;
        float bv = bias[c];
        #pragma unroll
        for (int rt = 0; rt < 4; ++rt) {
            #pragma unroll
            for (int q = 0; q < 4; ++q) {
                int r = row0 + rt * 16 + rb + q;
                if (r < n) C[(size_t)r * 768 + c] = f2h(relu_f(acc[rt][ct][q] + bv));
            }
        }
    }
}

// ---------------- interleaved exact top-128 masks, early-exit search ----------------
// Identical results to the fixed-15-iteration version: once cge==128 (exact cut)
// or lo>=hi (converged to tie value), further iterations are no-ops and skipped.
template<int CNT>
__device__ __forceinline__ void topk_multi(const ushort4* hu, const float4* v, float4* out) {
    int lane = threadIdx.x & 63;
    unsigned lo[CNT], hi[CNT]; int cge[CNT];
    #pragma unroll
    for (int s = 0; s < CNT; ++s) {
        unsigned mx = max(max((unsigned)hu[s].x, (unsigned)hu[s].y),
                          max((unsigned)hu[s].z, (unsigned)hu[s].w));
        #pragma unroll
        for (int off = 32; off >= 1; off >>= 1)
            mx = max(mx, (unsigned)__shfl_xor((int)mx, off));
        lo[s] = 0; hi[s] = mx; cge[s] = 256;
    }
    for (int it = 0; it < 15; ++it) {
        #pragma unroll
        for (int s = 0; s < CNT; ++s) {
            if (cge[s] == 128 || lo[s] >= hi[s]) continue;   // wave-uniform skip
            unsigned mid = (lo[s] + hi[s] + 1) >> 1;
            int c = __popcll(__ballot(hu[s].x >= mid)) + __popcll(__ballot(hu[s].y >= mid))
                  + __popcll(__ballot(hu[s].z >= mid)) + __popcll(__ballot(hu[s].w >= mid));
            if (c >= 128) { lo[s] = mid; cge[s] = c; } else hi[s] = mid - 1;
        }
    }
    #pragma unroll
    for (int s = 0; s < CNT; ++s) {
        unsigned thr = lo[s];
        unsigned a0 = hu[s].x, a1 = hu[s].y, a2 = hu[s].z, a3 = hu[s].w;
        float4 r;
        if (cge[s] == 128) {
            r.x = (a0 >= thr) ? v[s].x : 0.f;
            r.y = (a1 >= thr) ? v[s].y : 0.f;
            r.z = (a2 >= thr) ? v[s].z : 0.f;
            r.w = (a3 >= thr) ? v[s].w : 0.f;
        } else {            // trim ties: keep lowest element indices among == thr
            ull b0 = __ballot(a0 == thr), b1 = __ballot(a1 == thr);
            ull b2 = __ballot(a2 == thr), b3 = __ballot(a3 == thr);
            int cgt = __popcll(__ballot(a0 > thr)) + __popcll(__ballot(a1 > thr))
                    + __popcll(__ballot(a2 > thr)) + __popcll(__ballot(a3 > thr));
            int need = 128 - cgt;
            ull below = (lane == 0) ? 0ull : (~0ull >> (64 - lane));
            int base = __popcll(b0 & below) + __popcll(b1 & below)
                     + __popcll(b2 & below) + __popcll(b3 & below);
            int o0 = (int)((b0 >> lane) & 1), o1 = (int)((b1 >> lane) & 1), o2 = (int)((b2 >> lane) & 1);
            int p0 = base, p1 = base + o0, p2 = p1 + o1, p3 = p2 + o2;
            r.x = (a0 > thr || (a0 == thr && p0 < need)) ? v[s].x : 0.f;
            r.y = (a1 > thr || (a1 == thr && p1 < need)) ? v[s].y : 0.f;
            r.z = (a2 > thr || (a2 == thr && p2 < need)) ? v[s].z : 0.f;
            r.w = (a3 > thr || (a3 == thr && p3 < need)) ? v[s].w : 0.f;
        }
        out[s] = r;
    }
}

__device__ __forceinline__ float4 dec4(ushort4 h) {
    float4 r; r.x = h2f(h.x); r.y = h2f(h.y); r.z = h2f(h.z); r.w = h2f(h.w);
    return r;
}
__device__ __forceinline__ void st4h(u16* p, size_t off, float4 v) {
    ushort4 o; o.x = f2h(v.x); o.y = f2h(v.y); o.z = f2h(v.z); o.w = f2h(v.w);
    ((ushort4*)p)[off] = o;
}

// layer 0: states <- relu(p_b + g*sum mask(p_b'))   [interleaved: node*192 + br*64 + lane]
__global__ __launch_bounds__(256) void fuse0_k(const float* __restrict__ gate_logit, int n) {
    int node = blockIdx.x * 4 + (threadIdx.x >> 6);
    if (node >= n) return;
    int lane = threadIdx.x & 63;
    size_t base4 = (size_t)node * 192 + lane;
    float g = 1.f / (1.f + expf(-gate_logit[0]));
    const ushort4* P = (const ushort4*)g_props;
    ushort4 hu[3]; float4 v[3], m[3];
    hu[0] = P[base4]; hu[1] = P[base4 + 64]; hu[2] = P[base4 + 128];
    v[0] = dec4(hu[0]); v[1] = dec4(hu[1]); v[2] = dec4(hu[2]);
    topk_multi<3>(hu, v, m);
    float4 o0, o1, o2;
    o0.x = relu_f(v[0].x + g * m[1].x); o0.y = relu_f(v[0].y + g * m[1].y);
    o0.z = relu_f(v[0].z + g * m[1].z); o0.w = relu_f(v[0].w + g * m[1].w);
    o1.x = relu_f(v[1].x + g * (m[0].x + m[2].x)); o1.y = relu_f(v[1].y + g * (m[0].y + m[2].y));
    o1.z = relu_f(v[1].z + g * (m[0].z + m[2].z)); o1.w = relu_f(v[1].w + g * (m[0].w + m[2].w));
    o2.x = relu_f(v[2].x + g * m[1].x); o2.y = relu_f(v[2].y + g * m[1].y);
    o2.z = relu_f(v[2].z + g * m[1].z); o2.w = relu_f(v[2].w + g * m[1].w);
    st4h(g_states, base4, o0); st4h(g_states, base4 + 64, o1); st4h(g_states, base4 + 128, o2);
}

// layers >=1: m[0..2]=mask(props), m[3..5]=mask(old states)
__global__ __launch_bounds__(256) void fuse_k(const float* __restrict__ gate_logit, int n) {
    int node = blockIdx.x * 4 + (threadIdx.x >> 6);
    if (node >= n) return;
    int lane = threadIdx.x & 63;
    size_t base4 = (size_t)node * 192 + lane;
    float g = 1.f / (1.f + expf(-gate_logit[0]));
    const ushort4* P = (const ushort4*)g_props;
    const ushort4* S = (const ushort4*)g_states;
    ushort4 hu[6]; float4 v[6], m[6];
    hu[0] = P[base4]; hu[1] = P[base4 + 64]; hu[2] = P[base4 + 128];
    hu[3] = S[base4]; hu[4] = S[base4 + 64]; hu[5] = S[base4 + 128];
    #pragma unroll
    for (int s = 0; s < 6; ++s) v[s] = dec4(hu[s]);
    topk_multi<6>(hu, v, m);
    float4 o0, o1, o2;
    o0.x = relu_f(v[0].x + g * (m[3].x + m[1].x + m[4].x));
    o0.y = relu_f(v[0].y + g * (m[3].y + m[1].y + m[4].y));
    o0.z = relu_f(v[0].z + g * (m[3].z + m[1].z + m[4].z));
    o0.w = relu_f(v[0].w + g * (m[3].w + m[1].w + m[4].w));
    o1.x = relu_f(v[1].x + g * (m[4].x + m[0].x + m[3].x + m[2].x + m[5].x));
    o1.y = relu_f(v[1].y + g * (m[4].y + m[0].y + m[3].y + m[2].y + m[5].y));
    o1.z = relu_f(v[1].z + g * (m[4].z + m[0].z + m[3].z + m[2].z + m[5].z));
    o1.w = relu_f(v[1].w + g * (m[4].w + m[0].w + m[3].w + m[2].w + m[5].w));
    o2.x = relu_f(v[2].x + g * (m[5].x + m[1].x + m[4].x));
    o2.y = relu_f(v[2].y + g * (m[5].y + m[1].y + m[4].y));
    o2.z = relu_f(v[2].z + g * (m[5].z + m[1].z + m[4].z));
    o2.w = relu_f(v[2].w + g * (m[5].w + m[1].w + m[4].w));
    st4h(g_states, base4, o0); st4h(g_states, base4 + 64, o1); st4h(g_states, base4 + 128, o2);
}

// ---------------- readout ----------------
__global__ void gbounds_k(const int* __restrict__ batch, int n) {
    int i = blockIdx.x * 256 + threadIdx.x;
    if (i >= n) return;
    int g = batch[i];
    atomicAdd(&g_gc[g], 1);
    if (i == 0 || batch[i - 1] != g) g_gs[g] = i;
}

__global__ __launch_bounds__(256) void greduce_k(float* __restrict__ outfin, int n) {
    __shared__ float sums[768];
    int g = blockIdx.x, t = threadIdx.x;
    int st = g_gs[g], c = g_gc[g];
    if (t < 192) {
        const ushort4* S = (const ushort4*)g_states;
        float a0 = 0.f, a1 = 0.f, a2 = 0.f, a3 = 0.f;
        for (int i = st; i < st + c; ++i) {
            ushort4 v = S[(size_t)i * 192 + t];
            a0 += h2f(v.x); a1 += h2f(v.y); a2 += h2f(v.z); a3 += h2f(v.w);
        }
        sums[t * 4 + 0] = a0; sums[t * 4 + 1] = a1;
        sums[t * 4 + 2] = a2; sums[t * 4 + 3] = a3;
    }
    __syncthreads();
    float r = (sums[t] + sums[256 + t] + sums[512 + t]) / (3.0f * (float)(c > 0 ? c : 1));
    g_fin[g * 256 + t] = r;
    outfin[(size_t)g * 256 + t] = r;
}

__global__ void logits_k(const float* __restrict__ Wc, const float* __restrict__ bc,
                         float* __restrict__ out) {
    int idx = blockIdx.x * 256 + threadIdx.x;
    if (idx >= NGRAPH * NCLS) return;
    int g = idx / NCLS, c = idx % NCLS;
    float s = bc[c];
    for (int k = 0; k < 256; ++k) s += g_fin[g * 256 + k] * Wc[k * NCLS + c];
    out[idx] = s;
}

// ---------------- launch ----------------
extern "C" void kernel_launch(void* const* d_in, const int* in_sizes, int n_in,
                              void* d_out, int out_size, void* d_ws, size_t ws_size,
                              hipStream_t stream) {
    const float* x       = (const float*)d_in[0];
    const int*   eidx    = (const int*)d_in[1];
    const int*   batch   = (const int*)d_in[2];
    const float* Win     = (const float*)d_in[3];
    const float* b_in    = (const float*)d_in[4];
    const float* Whid    = (const float*)d_in[5];
    const float* bhid    = (const float*)d_in[6];
    const float* gate_l  = (const float*)d_in[7];
    const float* Wc      = (const float*)d_in[8];
    const float* bc      = (const float*)d_in[9];
    float* out = (float*)d_out;

    const int n = in_sizes[0] / INDIM;       // 50000
    const int E = in_sizes[1] / 2;           // 800000
    if (n > NMAX || E > EMAX) return;
    const int* erow = eidx;
    const int* ecol = eidx + E;

    float* outfin = out + NGRAPH * NCLS;

    const int TB = 256;
    dim3 b256(TB);
    int nblkN = (n + TB - 1) / TB;
    int eblk  = (E + TB - 1) / TB;
    int nblk4 = (n + 3) / 4;
    int sblk  = (n + 1023) / 1024;
    dim3 ggrid((n + 63) / 64, NB);
    dim3 wgin(INDIM / 32, HIDDEN / 32, NB);
    dim3 wghid(HIDDEN / 32, HIDDEN / 32, 9);

    // --- conversions + CSR build ---
    zero_cnt_k<<<nblkN, b256, 0, stream>>>(n);
    cvt_xh_k<<<(n * INDIM / 4 + TB - 1) / TB, b256, 0, stream>>>(x, n * INDIM / 4);
    cvt_wt_k<<<wgin, b256, 0, stream>>>(Win, 0, INDIM);
    cvt_wt_k<<<wghid, b256, 0, stream>>>(Whid, 1, HIDDEN);
    count_edges_k<<<eblk, b256, 0, stream>>>(ecol, E);
    dinv_k<<<nblkN, b256, 0, stream>>>(n);
    scan1_k<<<sblk, 1024, 0, stream>>>(n);
    scan2_k<<<1, 64, 0, stream>>>(sblk);
    scan3_k<<<nblkN, b256, 0, stream>>>(n);
    zero_cnt_k<<<nblkN, b256, 0, stream>>>(n);
    fill_csr_k<<<eblk, b256, 0, stream>>>(erow, ecol, E);

    // --- layer 0 ---
    agg128_k<<<nblk4, b256, 0, stream>>>(n);
    gemm_mfma_k<INDIM><<<ggrid, b256, 0, stream>>>(-1, INDIM, 0, b_in, n);
    fuse0_k<<<nblk4, b256, 0, stream>>>(gate_l, n);

    // --- layers 1..3 ---
    for (int l = 1; l < 4; ++l) {
        agg256x3_k<<<nblk4, b256, 0, stream>>>(n);
        gemm_mfma_k<HIDDEN><<<ggrid, b256, 0, stream>>>((l - 1) * NB, NB * HIDDEN, HIDDEN,
                bhid + (size_t)(l - 1) * NB * HIDDEN, n);
        fuse_k<<<nblk4, b256, 0, stream>>>(gate_l, n);
    }

    // --- readout ---
    zero_gk<<<1, 256, 0, stream>>>();
    gbounds_k<<<nblkN, b256, 0, stream>>>(batch, n);
    greduce_k<<<NGRAPH, b256, 0, stream>>>(outfin, n);
    logits_k<<<(NGRAPH * NCLS + TB - 1) / TB, b256, 0, stream>>>(Wc, bc, out);
}